// Round 1
// baseline (1943.034 us; speedup 1.0000x reference)
//
#include <hip/hip_runtime.h>
#include <math.h>

#define BATCH 16384
#define EPSQ 1e-8f

// ---------------- ws layout (float offsets) ----------------
// scalars:
// [0] absmax_in
// [1] max_a1   [2] negmax_a1   (conv1 preact, pre-pool, incl bias)
// [3] max_a2   [4] negmax_a2   (conv2 preact)
// [5] max_a3   [6] negmax_a3   (fc1 preact)
// [7] max_a4   [8] negmax_a4   (fc2 preact)
#define OFF_SCAL 0
#define OFF_WQ1  16                         // 450   (6,3,5,5) quantized +-s
#define OFF_WQ2  (16+450)                   // 2400  (16,6,5,5)
#define OFF_F1T  (16+450+2400)              // 48000 transposed [400][120]
#define OFF_F2T  (OFF_F1T+48000)            // 10080 transposed [120][84]
#define OFF_F3T  (OFF_F2T+10080)            // 840   transposed [84][10]
#define OFF_OUT1 62016                      // B*6*14*14 pooled conv1 preact
#define N_OUT1   (BATCH*6*14*14)
#define OFF_OUT2 (OFF_OUT1+N_OUT1)          // B*400 pooled conv2 preact
#define N_OUT2   (BATCH*400)
#define OFF_P3   (OFF_OUT2+N_OUT2)          // B*120 fc1 preact
#define N_P3     (BATCH*120)
#define OFF_P4   (OFF_P3+N_P3)              // B*84  fc2 preact
#define N_P4     (BATCH*84)

__device__ inline void atomicMaxF(float* addr, float val) {
    unsigned int* ua = (unsigned int*)addr;
    unsigned int old = *ua;
    while (__uint_as_float(old) < val) {
        unsigned int assumed = old;
        old = atomicCAS(ua, assumed, __float_as_uint(val));
        if (old == assumed) break;
    }
}

__device__ inline float waveMax(float v) {
    #pragma unroll
    for (int off = 32; off > 0; off >>= 1)
        v = fmaxf(v, __shfl_down(v, off, 64));
    return v;
}

// block is always 256 threads = 4 waves in callers
__device__ inline void blockAtomicMax2(float vmax, float vnmax, float* gmax, float* gnmax) {
    __shared__ float sm[4], sn[4];
    float a = waveMax(vmax), b = waveMax(vnmax);
    int tid = threadIdx.x;
    if ((tid & 63) == 0) { sm[tid >> 6] = a; sn[tid >> 6] = b; }
    __syncthreads();
    if (tid == 0) {
        float m  = fmaxf(fmaxf(sm[0], sm[1]), fmaxf(sm[2], sm[3]));
        float n  = fmaxf(fmaxf(sn[0], sn[1]), fmaxf(sn[2], sn[3]));
        atomicMaxF(gmax, m);
        atomicMaxF(gnmax, n);
    }
}

// int8 fake-quant elementwise (forward value)
__device__ inline float fq_elem(float x, float s) {
    float q = fminf(fmaxf(rintf(x / s), -128.0f), 127.0f);
    return q * s;
}

// qrelu applied to a preact value given the two scales
__device__ inline float qrelu_elem(float x, float s1, float s2) {
    float q = fq_elem(x, s1);
    q = fmaxf(q, 0.0f);
    return fq_elem(q, s2);
}

// derive (s1, s2) for qrelu from stored (max, negmax) of the preact tensor
__device__ inline void get_qrelu_scales(const float* scal, int slot, float& s1, float& s2) {
    float maxa = scal[slot], negm = scal[slot + 1];
    float absm = fmaxf(maxa, negm);
    s1 = fmaxf(absm / 127.0f, EPSQ);
    float qm = fminf(fmaxf(rintf(maxa / s1), -128.0f), 127.0f) * s1;  // fq of max
    s2 = fmaxf(fmaxf(qm, 0.0f) / 127.0f, EPSQ);                       // relu then /127
}

// ---------------- prep: init scalars + binarize weights ----------------
__global__ __launch_bounds__(256) void prep_kernel(const float* __restrict__ w1,
        const float* __restrict__ w2, const float* __restrict__ fw1,
        const float* __restrict__ fw2, const float* __restrict__ fw3,
        float* __restrict__ ws) {
    int blk = blockIdx.x, tid = threadIdx.x;
    float* scal = ws + OFF_SCAL;
    if (blk == 0) {
        if (tid == 0) scal[0] = 0.0f;
        else if (tid <= 8) scal[tid] = -INFINITY;
        return;
    }
    const float* src = nullptr; float* dst = nullptr;
    int N = 0, C = 0, R = 0, mode = 0;
    if (blk == 1)      { src = w1;  dst = ws + OFF_WQ1; N = 450;   mode = 0; }
    else if (blk == 2) { src = w2;  dst = ws + OFF_WQ2; N = 2400;  mode = 0; }
    else if (blk == 3) { src = fw1; dst = ws + OFF_F1T; N = 48000; R = 120; C = 400; mode = 1; }
    else if (blk == 4) { src = fw2; dst = ws + OFF_F2T; N = 10080; R = 84;  C = 120; mode = 1; }
    else               { src = fw3; dst = ws + OFF_F3T; N = 840;   R = 10;  C = 84;  mode = 1; }
    __shared__ float red[256];
    __shared__ float sS;
    float partial = 0.0f;
    for (int i = tid; i < N; i += 256) partial += fabsf(src[i]);
    red[tid] = partial;
    __syncthreads();
    for (int s = 128; s > 0; s >>= 1) {
        if (tid < s) red[tid] += red[tid + s];
        __syncthreads();
    }
    if (tid == 0) sS = red[0] / (float)N;
    __syncthreads();
    float s = sS;
    if (mode == 0) {
        for (int i = tid; i < N; i += 256) dst[i] = (src[i] >= 0.0f) ? s : -s;
    } else {
        for (int i = tid; i < N; i += 256) {
            int r = i / C, c = i % C;
            dst[c * R + r] = (src[i] >= 0.0f) ? s : -s;   // transpose for coalesced GEMM reads
        }
    }
}

// ---------------- input abs-max ----------------
__global__ __launch_bounds__(256) void absmax_kernel(const float4* __restrict__ x, int n4,
                                                     float* __restrict__ gmax) {
    float m = 0.0f;
    int stride = gridDim.x * 256;
    for (int i = blockIdx.x * 256 + threadIdx.x; i < n4; i += stride) {
        float4 v = x[i];
        m = fmaxf(m, fmaxf(fmaxf(fabsf(v.x), fabsf(v.y)), fmaxf(fabsf(v.z), fabsf(v.w))));
    }
    m = waveMax(m);
    if ((threadIdx.x & 63) == 0) atomicMaxF(gmax, m);
}

// ---------------- conv1 (5x5, 3->6) + bias + maxpool2, one image per block ----------------
__global__ __launch_bounds__(256) void conv1_kernel(const float* __restrict__ x,
        const float* __restrict__ b1, float* __restrict__ ws) {
    __shared__ float xq[3072];    // [3][32][32] quantized input
    __shared__ float wsm[450];    // [6][3][25]
    float* scal = ws + OFF_SCAL;
    float* out1 = ws + OFF_OUT1;
    int b = blockIdx.x, tid = threadIdx.x;
    float s0 = fmaxf(scal[0] / 127.0f, EPSQ);
    const float* xb = x + (size_t)b * 3072;
    for (int i = tid; i < 3072; i += 256) xq[i] = fq_elem(xb[i], s0);
    const float* wq1 = ws + OFF_WQ1;
    for (int i = tid; i < 450; i += 256) wsm[i] = wq1[i];
    __syncthreads();
    float vmax = -INFINITY, vnmax = -INFINITY;
    for (int p = tid; p < 1176; p += 256) {
        int c = p / 196, pos = p % 196;
        int py = pos / 14, px = pos % 14;
        int oy = py * 2, ox = px * 2;
        float a00 = 0.f, a01 = 0.f, a10 = 0.f, a11 = 0.f;
        const float* wc = &wsm[c * 75];
        for (int ci = 0; ci < 3; ci++) {
            float win[6][6];
            const float* xc = &xq[ci * 1024 + oy * 32 + ox];
            #pragma unroll
            for (int r = 0; r < 6; r++)
                #pragma unroll
                for (int q2 = 0; q2 < 6; q2++)
                    win[r][q2] = xc[r * 32 + q2];
            const float* wi = wc + ci * 25;
            #pragma unroll
            for (int ky = 0; ky < 5; ky++)
                #pragma unroll
                for (int kx = 0; kx < 5; kx++) {
                    float w = wi[ky * 5 + kx];
                    a00 = fmaf(win[ky][kx],     w, a00);
                    a01 = fmaf(win[ky][kx+1],   w, a01);
                    a10 = fmaf(win[ky+1][kx],   w, a10);
                    a11 = fmaf(win[ky+1][kx+1], w, a11);
                }
        }
        float bias = b1[c];
        a00 += bias; a01 += bias; a10 += bias; a11 += bias;
        float mx = fmaxf(fmaxf(a00, a01), fmaxf(a10, a11));
        float mn = fminf(fminf(a00, a01), fminf(a10, a11));
        vmax  = fmaxf(vmax, mx);
        vnmax = fmaxf(vnmax, -mn);
        out1[(size_t)b * 1176 + p] = mx;   // pooled preact (quantize later: monotone)
    }
    blockAtomicMax2(vmax, vnmax, scal + 1, scal + 2);
}

// ---------------- conv2 (5x5, 6->16) + bias + maxpool2 ----------------
__global__ __launch_bounds__(256) void conv2_kernel(const float* __restrict__ b2,
                                                    float* __restrict__ ws) {
    __shared__ float act[1176];   // [6][14][14] quantized activations
    __shared__ float wsm[2400];   // [16][6][25]
    float* scal = ws + OFF_SCAL;
    const float* out1 = ws + OFF_OUT1;
    float* out2 = ws + OFF_OUT2;
    int b = blockIdx.x, tid = threadIdx.x;
    float s1, s2;
    get_qrelu_scales(scal, 1, s1, s2);
    for (int i = tid; i < 1176; i += 256)
        act[i] = qrelu_elem(out1[(size_t)b * 1176 + i], s1, s2);
    const float* wq2 = ws + OFF_WQ2;
    for (int i = tid; i < 2400; i += 256) wsm[i] = wq2[i];
    __syncthreads();
    float vmax = -INFINITY, vnmax = -INFINITY;
    for (int p = tid; p < 400; p += 256) {
        int c = p / 25, pos = p % 25;
        int py = pos / 5, px = pos % 5;
        int oy = py * 2, ox = px * 2;
        float a00 = 0.f, a01 = 0.f, a10 = 0.f, a11 = 0.f;
        const float* wc = &wsm[c * 150];
        for (int ci = 0; ci < 6; ci++) {
            float win[6][6];
            const float* xc = &act[ci * 196 + oy * 14 + ox];
            #pragma unroll
            for (int r = 0; r < 6; r++)
                #pragma unroll
                for (int q2 = 0; q2 < 6; q2++)
                    win[r][q2] = xc[r * 14 + q2];
            const float* wi = wc + ci * 25;
            #pragma unroll
            for (int ky = 0; ky < 5; ky++)
                #pragma unroll
                for (int kx = 0; kx < 5; kx++) {
                    float w = wi[ky * 5 + kx];
                    a00 = fmaf(win[ky][kx],     w, a00);
                    a01 = fmaf(win[ky][kx+1],   w, a01);
                    a10 = fmaf(win[ky+1][kx],   w, a10);
                    a11 = fmaf(win[ky+1][kx+1], w, a11);
                }
        }
        float bias = b2[c];
        a00 += bias; a01 += bias; a10 += bias; a11 += bias;
        float mx = fmaxf(fmaxf(a00, a01), fmaxf(a10, a11));
        float mn = fminf(fminf(a00, a01), fminf(a10, a11));
        vmax  = fmaxf(vmax, mx);
        vnmax = fmaxf(vnmax, -mn);
        out2[(size_t)b * 400 + p] = mx;   // matches reshape(B, 16*5*5)
    }
    blockAtomicMax2(vmax, vnmax, scal + 3, scal + 4);
}

// ---------------- fc1: [B,400] -> [B,120], 2 rows per block ----------------
__global__ __launch_bounds__(256) void fc1_kernel(const float* __restrict__ fb1,
                                                  float* __restrict__ ws) {
    __shared__ float xs[2][400];
    float* scal = ws + OFF_SCAL;
    const float* p2 = ws + OFF_OUT2;
    const float* wT = ws + OFF_F1T;   // [400][120]
    float* p3 = ws + OFF_P3;
    int tid = threadIdx.x;
    size_t row0 = (size_t)blockIdx.x * 2;
    float s1, s2;
    get_qrelu_scales(scal, 3, s1, s2);
    for (int i = tid; i < 800; i += 256) {
        int r = i / 400, k = i % 400;
        xs[r][k] = qrelu_elem(p2[(row0 + r) * 400 + k], s1, s2);
    }
    __syncthreads();
    float vmax = -INFINITY, vnmax = -INFINITY;
    if (tid < 240) {
        int r = tid / 120, j = tid % 120;
        float acc = fb1[j];
        #pragma unroll 8
        for (int k = 0; k < 400; k++)
            acc = fmaf(xs[r][k], wT[k * 120 + j], acc);
        p3[(row0 + r) * 120 + j] = acc;
        vmax = acc; vnmax = -acc;
    }
    blockAtomicMax2(vmax, vnmax, scal + 5, scal + 6);
}

// ---------------- fc2: [B,120] -> [B,84], 3 rows per block ----------------
__global__ __launch_bounds__(256) void fc2_kernel(const float* __restrict__ fb2,
                                                  float* __restrict__ ws) {
    __shared__ float xs[3][120];
    float* scal = ws + OFF_SCAL;
    const float* p3 = ws + OFF_P3;
    const float* wT = ws + OFF_F2T;   // [120][84]
    float* p4 = ws + OFF_P4;
    int tid = threadIdx.x;
    size_t row0 = (size_t)blockIdx.x * 3;
    float s1, s2;
    get_qrelu_scales(scal, 5, s1, s2);
    for (int i = tid; i < 360; i += 256) {
        int r = i / 120, k = i % 120;
        size_t row = row0 + r;
        xs[r][k] = (row < BATCH) ? qrelu_elem(p3[row * 120 + k], s1, s2) : 0.0f;
    }
    __syncthreads();
    float vmax = -INFINITY, vnmax = -INFINITY;
    if (tid < 252) {
        int r = tid / 84, j = tid % 84;
        size_t row = row0 + r;
        if (row < BATCH) {
            float acc = fb2[j];
            #pragma unroll 8
            for (int k = 0; k < 120; k++)
                acc = fmaf(xs[r][k], wT[k * 84 + j], acc);
            p4[row * 84 + j] = acc;
            vmax = acc; vnmax = -acc;
        }
    }
    blockAtomicMax2(vmax, vnmax, scal + 7, scal + 8);
}

// ---------------- fc3: [B,84] -> [B,10], 25 rows per block ----------------
__global__ __launch_bounds__(256) void fc3_kernel(const float* __restrict__ fb3,
                                                  float* __restrict__ out,
                                                  float* __restrict__ ws) {
    __shared__ float xs[25][84];
    float* scal = ws + OFF_SCAL;
    const float* p4 = ws + OFF_P4;
    const float* wT = ws + OFF_F3T;   // [84][10]
    int tid = threadIdx.x;
    size_t row0 = (size_t)blockIdx.x * 25;
    float s1, s2;
    get_qrelu_scales(scal, 7, s1, s2);
    for (int i = tid; i < 2100; i += 256) {
        int r = i / 84, k = i % 84;
        size_t row = row0 + r;
        if (row < BATCH) xs[r][k] = qrelu_elem(p4[row * 84 + k], s1, s2);
    }
    __syncthreads();
    if (tid < 250) {
        int r = tid / 10, j = tid % 10;
        size_t row = row0 + r;
        if (row < BATCH) {
            float acc = fb3[j];
            #pragma unroll
            for (int k = 0; k < 84; k++)
                acc = fmaf(xs[r][k], wT[k * 10 + j], acc);
            out[row * 10 + j] = acc;
        }
    }
}

extern "C" void kernel_launch(void* const* d_in, const int* in_sizes, int n_in,
                              void* d_out, int out_size, void* d_ws, size_t ws_size,
                              hipStream_t stream) {
    const float* input = (const float*)d_in[0];
    const float* w1  = (const float*)d_in[1];
    const float* b1  = (const float*)d_in[2];
    const float* w2  = (const float*)d_in[3];
    const float* b2  = (const float*)d_in[4];
    const float* fw1 = (const float*)d_in[5];
    const float* fb1 = (const float*)d_in[6];
    const float* fw2 = (const float*)d_in[7];
    const float* fb2 = (const float*)d_in[8];
    const float* fw3 = (const float*)d_in[9];
    const float* fb3 = (const float*)d_in[10];
    float* ws  = (float*)d_ws;
    float* out = (float*)d_out;

    prep_kernel<<<6, 256, 0, stream>>>(w1, w2, fw1, fw2, fw3, ws);
    absmax_kernel<<<2048, 256, 0, stream>>>((const float4*)input,
                                            (int)((size_t)BATCH * 3072 / 4), ws + OFF_SCAL);
    conv1_kernel<<<BATCH, 256, 0, stream>>>(input, b1, ws);
    conv2_kernel<<<BATCH, 256, 0, stream>>>(b2, ws);
    fc1_kernel<<<BATCH / 2, 256, 0, stream>>>(fb1, ws);
    fc2_kernel<<<(BATCH + 2) / 3, 256, 0, stream>>>(fb2, ws);
    fc3_kernel<<<(BATCH + 24) / 25, 256, 0, stream>>>(fb3, out, ws);
}

// Round 2
// 991.134 us; speedup vs baseline: 1.9604x; 1.9604x over previous
//
#include <hip/hip_runtime.h>
#include <math.h>

#define BATCH 16384
#define EPSQ 1e-8f

// ---------------- ws layout (float offsets) ----------------
// scalars: [0] absmax_in
// [1] max_a1 [2] negmax_a1 (conv1 preact, pre-pool, incl bias)
// [3] max_a2 [4] negmax_a2 (conv2 preact)
// [5] max_a3 [6] negmax_a3 (fc1 preact)
// [7] max_a4 [8] negmax_a4 (fc2 preact)
#define OFF_SCAL 0
#define OFF_WQ1  16                         // 450   (6,3,5,5) binarized +-s
#define OFF_WQ2  (16+450)                   // 2400  (16,6,5,5)
#define OFF_FQ1  (16+450+2400)              // 48000 [120][400] binarized (no transpose)
#define OFF_FQ2  (OFF_FQ1+48000)            // 10080 [84][120]
#define OFF_FQ3  (OFF_FQ2+10080)            // 840   [10][84]
#define OFF_OUT1 62016                      // B*6*14*14 pooled conv1 preact
#define N_OUT1   (BATCH*6*14*14)
#define OFF_OUT2 (OFF_OUT1+N_OUT1)          // B*400 pooled conv2 preact
#define N_OUT2   (BATCH*400)
#define OFF_P3   (OFF_OUT2+N_OUT2)          // B*120 fc1 preact
#define N_P3     (BATCH*120)
#define OFF_P4   (OFF_P3+N_P3)              // B*84  fc2 preact
#define N_P4     (BATCH*84)

__device__ inline void atomicMaxF(float* addr, float val) {
    unsigned int* ua = (unsigned int*)addr;
    unsigned int old = *ua;
    while (__uint_as_float(old) < val) {
        unsigned int assumed = old;
        old = atomicCAS(ua, assumed, __float_as_uint(val));
        if (old == assumed) break;
    }
}

__device__ inline float waveMax(float v) {
    #pragma unroll
    for (int off = 32; off > 0; off >>= 1)
        v = fmaxf(v, __shfl_down(v, off, 64));
    return v;
}

// block of 256 threads = 4 waves
__device__ inline void blockAtomicMax2(float vmax, float vnmax, float* gmax, float* gnmax) {
    __shared__ float sm[4], sn[4];
    float a = waveMax(vmax), b = waveMax(vnmax);
    int tid = threadIdx.x;
    if ((tid & 63) == 0) { sm[tid >> 6] = a; sn[tid >> 6] = b; }
    __syncthreads();
    if (tid == 0) {
        float m = fmaxf(fmaxf(sm[0], sm[1]), fmaxf(sm[2], sm[3]));
        float n = fmaxf(fmaxf(sn[0], sn[1]), fmaxf(sn[2], sn[3]));
        atomicMaxF(gmax, m);
        atomicMaxF(gnmax, n);
    }
}

__device__ inline void waveAtomicMax2(float vmax, float vnmax, float* gmax, float* gnmax) {
    float a = waveMax(vmax), b = waveMax(vnmax);
    if ((threadIdx.x & 63) == 0) { atomicMaxF(gmax, a); atomicMaxF(gnmax, b); }
}

// int8 fake-quant (forward value). Use true IEEE division to match jnp.round(x/s).
__device__ inline float fq_elem(float x, float s) {
    float q = fminf(fmaxf(rintf(x / s), -128.0f), 127.0f);
    return q * s;
}

__device__ inline float qrelu_elem(float x, float s1, float s2) {
    float q = fq_elem(x, s1);
    q = fmaxf(q, 0.0f);
    return fq_elem(q, s2);
}

// derive (s1, s2) for qrelu from stored (max, negmax) of the preact tensor
__device__ inline void get_qrelu_scales(const float* scal, int slot, float& s1, float& s2) {
    float maxa = scal[slot], negm = scal[slot + 1];
    float absm = fmaxf(maxa, negm);
    s1 = fmaxf(absm / 127.0f, EPSQ);
    float qm = fminf(fmaxf(rintf(maxa / s1), -128.0f), 127.0f) * s1;
    s2 = fmaxf(fmaxf(qm, 0.0f) / 127.0f, EPSQ);
}

// ---------------- prep: init scalars + binarize weights ----------------
__global__ __launch_bounds__(256) void prep_kernel(const float* __restrict__ w1,
        const float* __restrict__ w2, const float* __restrict__ fw1,
        const float* __restrict__ fw2, const float* __restrict__ fw3,
        float* __restrict__ ws) {
    int blk = blockIdx.x, tid = threadIdx.x;
    float* scal = ws + OFF_SCAL;
    if (blk == 0) {
        if (tid == 0) scal[0] = 0.0f;
        else if (tid <= 8) scal[tid] = -INFINITY;
        return;
    }
    const float* src = nullptr; float* dst = nullptr; int N = 0;
    if (blk == 1)      { src = w1;  dst = ws + OFF_WQ1; N = 450; }
    else if (blk == 2) { src = w2;  dst = ws + OFF_WQ2; N = 2400; }
    else if (blk == 3) { src = fw1; dst = ws + OFF_FQ1; N = 48000; }
    else if (blk == 4) { src = fw2; dst = ws + OFF_FQ2; N = 10080; }
    else               { src = fw3; dst = ws + OFF_FQ3; N = 840; }
    __shared__ float red[256];
    __shared__ float sS;
    float partial = 0.0f;
    for (int i = tid; i < N; i += 256) partial += fabsf(src[i]);
    red[tid] = partial;
    __syncthreads();
    for (int s = 128; s > 0; s >>= 1) {
        if (tid < s) red[tid] += red[tid + s];
        __syncthreads();
    }
    if (tid == 0) sS = red[0] / (float)N;
    __syncthreads();
    float s = sS;
    for (int i = tid; i < N; i += 256) dst[i] = (src[i] >= 0.0f) ? s : -s;
}

// ---------------- input abs-max ----------------
__global__ __launch_bounds__(256) void absmax_kernel(const float4* __restrict__ x, int n4,
                                                     float* __restrict__ gmax) {
    float m = 0.0f;
    int stride = gridDim.x * 256;
    for (int i = blockIdx.x * 256 + threadIdx.x; i < n4; i += stride) {
        float4 v = x[i];
        m = fmaxf(m, fmaxf(fmaxf(fabsf(v.x), fabsf(v.y)), fmaxf(fabsf(v.z), fabsf(v.w))));
    }
    m = waveMax(m);
    if ((threadIdx.x & 63) == 0) atomicMaxF(gmax, m);
}

// ---------------- conv1: 3 images/block, row-sliding register conv ----------------
// LDS layout: xq[img][ci][32][36], img stride 3460 floats (bank stagger), ci stride 1152.
#define C1_IMGSTRIDE 3460
__global__ __launch_bounds__(256) void conv1_kernel(const float* __restrict__ x,
        const float* __restrict__ b1, float* __restrict__ ws) {
    __shared__ float xq[3 * C1_IMGSTRIDE];
    __shared__ float wsm[450];
    float* scal = ws + OFF_SCAL;
    float* out1 = ws + OFF_OUT1;
    int tid = threadIdx.x;
    int b0 = blockIdx.x * 3;
    int nimg = min(3, BATCH - b0);
    float s0 = fmaxf(scal[0] / 127.0f, EPSQ);

    // stage quantized input: nimg*768 float4 loads, coalesced
    const float4* xb = (const float4*)(x + (size_t)b0 * 3072);
    for (int i = tid; i < nimg * 768; i += 256) {
        float4 v = xb[i];
        v.x = fq_elem(v.x, s0); v.y = fq_elem(v.y, s0);
        v.z = fq_elem(v.z, s0); v.w = fq_elem(v.w, s0);
        int idx = i * 4;
        int img = idx / 3072, rem = idx % 3072;
        int ci = rem / 1024, r2 = rem % 1024;
        int row = r2 / 32, col = r2 % 32;
        *(float4*)&xq[img * C1_IMGSTRIDE + ci * 1152 + row * 36 + col] = v;
    }
    for (int i = tid; i < 450; i += 256) wsm[i] = ws[OFF_WQ1 + i];
    __syncthreads();

    float vmax = -INFINITY, vnmax = -INFINITY;
    if (tid < nimg * 84) {
        int img = tid / 84, r = tid % 84;
        int c = r / 14, py = r % 14;
        float bias = b1[c];
        float a0[28], a1[28];
        #pragma unroll
        for (int i = 0; i < 28; i++) { a0[i] = bias; a1[i] = bias; }
        const float* wc = &wsm[c * 75];
        for (int ci = 0; ci < 3; ci++) {
            const float* base = &xq[img * C1_IMGSTRIDE + ci * 1152 + (2 * py) * 36];
            const float* wci = wc + ci * 25;
            #pragma unroll
            for (int t = 0; t < 6; t++) {
                float row[32];
                #pragma unroll
                for (int k = 0; k < 8; k++)
                    *(float4*)&row[4 * k] = *(const float4*)&base[t * 36 + 4 * k];
                if (t <= 4) {
                    #pragma unroll
                    for (int kx = 0; kx < 5; kx++) {
                        float w0 = wci[t * 5 + kx];
                        #pragma unroll
                        for (int col = 0; col < 28; col++)
                            a0[col] = fmaf(row[col + kx], w0, a0[col]);
                    }
                }
                if (t >= 1) {
                    #pragma unroll
                    for (int kx = 0; kx < 5; kx++) {
                        float w1v = wci[(t - 1) * 5 + kx];
                        #pragma unroll
                        for (int col = 0; col < 28; col++)
                            a1[col] = fmaf(row[col + kx], w1v, a1[col]);
                    }
                }
            }
        }
        // min/max over ALL 56 pre-pool conv outputs (scales use full tensor)
        #pragma unroll
        for (int i = 0; i < 28; i++) {
            vmax  = fmaxf(vmax,  fmaxf(a0[i], a1[i]));
            vnmax = fmaxf(vnmax, fmaxf(-a0[i], -a1[i]));
        }
        // pooled preacts
        float* dst = &out1[(size_t)(b0 + img) * 1176 + c * 196 + py * 14];
        #pragma unroll
        for (int px = 0; px < 14; px++)
            dst[px] = fmaxf(fmaxf(a0[2 * px], a0[2 * px + 1]),
                            fmaxf(a1[2 * px], a1[2 * px + 1]));
    }
    blockAtomicMax2(vmax, vnmax, scal + 1, scal + 2);
}

// ---------------- conv2: 3 images/block ----------------
// LDS: act[img][ci][14][20], ci stride 280, img stride 1680
#define C2_IMGSTRIDE 1680
__global__ __launch_bounds__(256) void conv2_kernel(const float* __restrict__ b2,
                                                    float* __restrict__ ws) {
    __shared__ float act[3 * C2_IMGSTRIDE];
    __shared__ float wsm[2400];
    float* scal = ws + OFF_SCAL;
    const float* out1 = ws + OFF_OUT1;
    float* out2 = ws + OFF_OUT2;
    int tid = threadIdx.x;
    int b0 = blockIdx.x * 3;
    int nimg = min(3, BATCH - b0);
    float s1, s2;
    get_qrelu_scales(scal, 1, s1, s2);

    for (int i = tid; i < nimg * 1176; i += 256) {
        int img = i / 1176, rem = i % 1176;
        int ci = rem / 196, r2 = rem % 196;
        int row = r2 / 14, col = r2 % 14;
        float v = qrelu_elem(out1[(size_t)(b0 + img) * 1176 + rem], s1, s2);
        act[img * C2_IMGSTRIDE + ci * 280 + row * 20 + col] = v;
    }
    for (int i = tid; i < 2400; i += 256) wsm[i] = ws[OFF_WQ2 + i];
    __syncthreads();

    float vmax = -INFINITY, vnmax = -INFINITY;
    if (tid < nimg * 80) {
        int img = tid / 80, r = tid % 80;
        int c = r / 5, py = r % 5;
        float bias = b2[c];
        float a0[10], a1[10];
        #pragma unroll
        for (int i = 0; i < 10; i++) { a0[i] = bias; a1[i] = bias; }
        const float* wc = &wsm[c * 150];
        for (int ci = 0; ci < 6; ci++) {
            const float* base = &act[img * C2_IMGSTRIDE + ci * 280 + (2 * py) * 20];
            const float* wci = wc + ci * 25;
            #pragma unroll
            for (int t = 0; t < 6; t++) {
                float row[16];
                #pragma unroll
                for (int k = 0; k < 4; k++)
                    *(float4*)&row[4 * k] = *(const float4*)&base[t * 20 + 4 * k];
                if (t <= 4) {
                    #pragma unroll
                    for (int kx = 0; kx < 5; kx++) {
                        float w0 = wci[t * 5 + kx];
                        #pragma unroll
                        for (int col = 0; col < 10; col++)
                            a0[col] = fmaf(row[col + kx], w0, a0[col]);
                    }
                }
                if (t >= 1) {
                    #pragma unroll
                    for (int kx = 0; kx < 5; kx++) {
                        float w1v = wci[(t - 1) * 5 + kx];
                        #pragma unroll
                        for (int col = 0; col < 10; col++)
                            a1[col] = fmaf(row[col + kx], w1v, a1[col]);
                    }
                }
            }
        }
        #pragma unroll
        for (int i = 0; i < 10; i++) {
            vmax  = fmaxf(vmax,  fmaxf(a0[i], a1[i]));
            vnmax = fmaxf(vnmax, fmaxf(-a0[i], -a1[i]));
        }
        float* dst = &out2[(size_t)(b0 + img) * 400 + c * 25 + py * 5];
        #pragma unroll
        for (int px = 0; px < 5; px++)
            dst[px] = fmaxf(fmaxf(a0[2 * px], a0[2 * px + 1]),
                            fmaxf(a1[2 * px], a1[2 * px + 1]));
    }
    blockAtomicMax2(vmax, vnmax, scal + 3, scal + 4);
}

// ---------------- fc1: [B,400]->[B,120], 8 rows/block, thread j owns 8 rows ----------------
__global__ __launch_bounds__(128) void fc1_kernel(const float* __restrict__ fb1,
                                                  float* __restrict__ ws) {
    __shared__ float xs[8][400];
    float* scal = ws + OFF_SCAL;
    const float* p2 = ws + OFF_OUT2;
    const float* wq = ws + OFF_FQ1;   // [120][400]
    float* p3 = ws + OFF_P3;
    int tid = threadIdx.x;
    size_t row0 = (size_t)blockIdx.x * 8;
    float s1, s2;
    get_qrelu_scales(scal, 3, s1, s2);
    const float4* src = (const float4*)(p2 + row0 * 400);
    for (int i = tid; i < 800; i += 128) {
        float4 v = src[i];
        v.x = qrelu_elem(v.x, s1, s2); v.y = qrelu_elem(v.y, s1, s2);
        v.z = qrelu_elem(v.z, s1, s2); v.w = qrelu_elem(v.w, s1, s2);
        ((float4*)xs)[i] = v;
    }
    __syncthreads();
    float vmax = -INFINITY, vnmax = -INFINITY;
    if (tid < 120) {
        int j = tid;
        float acc[8];
        float bias = fb1[j];
        #pragma unroll
        for (int r = 0; r < 8; r++) acc[r] = bias;
        const float4* wr = (const float4*)(wq + j * 400);
        for (int k4 = 0; k4 < 100; k4++) {
            float4 w = wr[k4];
            #pragma unroll
            for (int r = 0; r < 8; r++) {
                float4 xv = *(const float4*)&xs[r][k4 * 4];
                acc[r] = fmaf(xv.x, w.x, acc[r]);
                acc[r] = fmaf(xv.y, w.y, acc[r]);
                acc[r] = fmaf(xv.z, w.z, acc[r]);
                acc[r] = fmaf(xv.w, w.w, acc[r]);
            }
        }
        #pragma unroll
        for (int r = 0; r < 8; r++) {
            p3[(row0 + r) * 120 + j] = acc[r];
            vmax = fmaxf(vmax, acc[r]); vnmax = fmaxf(vnmax, -acc[r]);
        }
    }
    waveAtomicMax2(vmax, vnmax, scal + 5, scal + 6);
}

// ---------------- fc2: [B,120]->[B,84], 8 rows/block ----------------
__global__ __launch_bounds__(128) void fc2_kernel(const float* __restrict__ fb2,
                                                  float* __restrict__ ws) {
    __shared__ float xs[8][120];
    float* scal = ws + OFF_SCAL;
    const float* p3 = ws + OFF_P3;
    const float* wq = ws + OFF_FQ2;   // [84][120]
    float* p4 = ws + OFF_P4;
    int tid = threadIdx.x;
    size_t row0 = (size_t)blockIdx.x * 8;
    float s1, s2;
    get_qrelu_scales(scal, 5, s1, s2);
    const float4* src = (const float4*)(p3 + row0 * 120);
    for (int i = tid; i < 240; i += 128) {
        float4 v = src[i];
        v.x = qrelu_elem(v.x, s1, s2); v.y = qrelu_elem(v.y, s1, s2);
        v.z = qrelu_elem(v.z, s1, s2); v.w = qrelu_elem(v.w, s1, s2);
        ((float4*)xs)[i] = v;
    }
    __syncthreads();
    float vmax = -INFINITY, vnmax = -INFINITY;
    if (tid < 84) {
        int j = tid;
        float acc[8];
        float bias = fb2[j];
        #pragma unroll
        for (int r = 0; r < 8; r++) acc[r] = bias;
        const float4* wr = (const float4*)(wq + j * 120);
        for (int k4 = 0; k4 < 30; k4++) {
            float4 w = wr[k4];
            #pragma unroll
            for (int r = 0; r < 8; r++) {
                float4 xv = *(const float4*)&xs[r][k4 * 4];
                acc[r] = fmaf(xv.x, w.x, acc[r]);
                acc[r] = fmaf(xv.y, w.y, acc[r]);
                acc[r] = fmaf(xv.z, w.z, acc[r]);
                acc[r] = fmaf(xv.w, w.w, acc[r]);
            }
        }
        #pragma unroll
        for (int r = 0; r < 8; r++) {
            p4[(row0 + r) * 84 + j] = acc[r];
            vmax = fmaxf(vmax, acc[r]); vnmax = fmaxf(vnmax, -acc[r]);
        }
    }
    waveAtomicMax2(vmax, vnmax, scal + 7, scal + 8);
}

// ---------------- fc3: [B,84]->[B,10], 1 row/thread ----------------
__global__ __launch_bounds__(256) void fc3_kernel(const float* __restrict__ fb3,
                                                  float* __restrict__ out,
                                                  float* __restrict__ ws) {
    __shared__ float wsm[840];
    __shared__ float bs[10];
    float* scal = ws + OFF_SCAL;
    const float* p4 = ws + OFF_P4;
    int tid = threadIdx.x;
    for (int i = tid; i < 840; i += 256) wsm[i] = ws[OFF_FQ3 + i];
    if (tid < 10) bs[tid] = fb3[tid];
    __syncthreads();
    float s1, s2;
    get_qrelu_scales(scal, 7, s1, s2);
    size_t row = (size_t)blockIdx.x * 256 + tid;
    float acc[10];
    #pragma unroll
    for (int j = 0; j < 10; j++) acc[j] = bs[j];
    const float4* src = (const float4*)(p4 + row * 84);
    for (int k4 = 0; k4 < 21; k4++) {
        float4 v = src[k4];
        v.x = qrelu_elem(v.x, s1, s2); v.y = qrelu_elem(v.y, s1, s2);
        v.z = qrelu_elem(v.z, s1, s2); v.w = qrelu_elem(v.w, s1, s2);
        #pragma unroll
        for (int j = 0; j < 10; j++) {
            acc[j] = fmaf(v.x, wsm[j * 84 + k4 * 4 + 0], acc[j]);
            acc[j] = fmaf(v.y, wsm[j * 84 + k4 * 4 + 1], acc[j]);
            acc[j] = fmaf(v.z, wsm[j * 84 + k4 * 4 + 2], acc[j]);
            acc[j] = fmaf(v.w, wsm[j * 84 + k4 * 4 + 3], acc[j]);
        }
    }
    #pragma unroll
    for (int j = 0; j < 10; j++) out[row * 10 + j] = acc[j];
}

extern "C" void kernel_launch(void* const* d_in, const int* in_sizes, int n_in,
                              void* d_out, int out_size, void* d_ws, size_t ws_size,
                              hipStream_t stream) {
    const float* input = (const float*)d_in[0];
    const float* w1  = (const float*)d_in[1];
    const float* b1  = (const float*)d_in[2];
    const float* w2  = (const float*)d_in[3];
    const float* b2  = (const float*)d_in[4];
    const float* fw1 = (const float*)d_in[5];
    const float* fb1 = (const float*)d_in[6];
    const float* fw2 = (const float*)d_in[7];
    const float* fb2 = (const float*)d_in[8];
    const float* fw3 = (const float*)d_in[9];
    const float* fb3 = (const float*)d_in[10];
    float* ws  = (float*)d_ws;
    float* out = (float*)d_out;

    prep_kernel<<<6, 256, 0, stream>>>(w1, w2, fw1, fw2, fw3, ws);
    absmax_kernel<<<2048, 256, 0, stream>>>((const float4*)input,
                                            (int)((size_t)BATCH * 3072 / 4), ws + OFF_SCAL);
    conv1_kernel<<<(BATCH + 2) / 3, 256, 0, stream>>>(input, b1, ws);
    conv2_kernel<<<(BATCH + 2) / 3, 256, 0, stream>>>(b2, ws);
    fc1_kernel<<<BATCH / 8, 128, 0, stream>>>(fb1, ws);
    fc2_kernel<<<BATCH / 8, 128, 0, stream>>>(fb2, ws);
    fc3_kernel<<<BATCH / 256, 256, 0, stream>>>(fb3, out, ws);
}